// Round 5
// baseline (2293.395 us; speedup 1.0000x reference)
//
#include <hip/hip_runtime.h>
#include <cstdint>

#define B_   8
#define N_   8192
#define M_   2048
#define CIN  64
#define COUT 128

typedef unsigned long long u64;

__device__ __forceinline__ float sq3(float dx, float dy, float dz) {
    return __fadd_rn(__fadd_rn(__fmul_rn(dx, dx), __fmul_rn(dy, dy)), __fmul_rn(dz, dz));
}

// ---------------- phase1: blocks 0..7 = FPS (one/batch), blocks 8..519 = GEMM tiles ----------------
// FPS: 512 thr x 16 pts IN REGISTERS (64 array VGPRs -> no LDS eviction, unlike R4's 256x32),
// point cloud in 96KB static LDS for staging/broadcast, f64-packed-key argmax
// (key = f64(dist) | (8191-idx) in low mantissa bits -> v_max_f64 == exact (max dist, tie->min idx)).
__global__ __launch_bounds__(512) void phase1_kernel(const float* __restrict__ p1, float* __restrict__ p2,
                                                     const float* __restrict__ x, const float* __restrict__ W,
                                                     float* __restrict__ h) {
    __shared__ __align__(16) char smem[98432];   // static: gfx950 allows up to 160KB/WG
    int t = threadIdx.x;

    if (blockIdx.x < B_) {
        // -------- FPS --------
        float2* lds_xy = (float2*)smem;                 // 8192*8B = 64KB
        float*  lds_z  = (float*)(smem + 65536);        // 8192*4B = 32KB
        double* wbest  = (double*)(smem + 98304);       // 2 bufs x 8 waves

        int b = blockIdx.x;
        const float* pb = p1 + (size_t)b * N_ * 3;
        float* p2b = p2 + (size_t)b * M_ * 3;
        int lane = t & 63, wave = t >> 6;

        for (int i = t; i < N_; i += 512) {
            lds_xy[i] = make_float2(pb[3 * i], pb[3 * i + 1]);
            lds_z[i]  = pb[3 * i + 2];
        }
        __syncthreads();

        // resident points + dists in registers (idx = t + j*512): 16x4 = 64 VGPRs
        float px[16], py[16], pz[16], dist[16];
#pragma unroll
        for (int j = 0; j < 16; ++j) {
            int idx = t + j * 512;
            float2 xy = lds_xy[idx];
            px[j] = xy.x; py[j] = xy.y; pz[j] = lds_z[idx];
            dist[j] = 1e10f;
        }

        float2 s0 = lds_xy[0];
        float sx = s0.x, sy = s0.y, sz = lds_z[0];
        if (t == 0) { p2b[0] = sx; p2b[1] = sy; p2b[2] = sz; }

        for (int i = 1; i < M_; ++i) {
            float bestv = -1.0f; int besti = 0;
#pragma unroll
            for (int j = 0; j < 16; ++j) {
                float d = sq3(__fsub_rn(px[j], sx), __fsub_rn(py[j], sy), __fsub_rn(pz[j], sz));
                float nd = fminf(dist[j], d);
                dist[j] = nd;
                if (nd > bestv) { bestv = nd; besti = t + j * 512; }  // strict >: first occurrence
            }
            // f64 key: exact value ordering, tie -> min index; v_max_f64 reduce
            double key = __longlong_as_double(__double_as_longlong((double)bestv) | (u64)(8191 - besti));
#pragma unroll
            for (int off = 32; off >= 1; off >>= 1)
                key = fmax(key, __shfl_xor(key, off));
            int buf = (i & 1) << 3;                      // double-buffer -> 1 barrier/iter
            if (lane == 0) wbest[buf + wave] = key;
            __syncthreads();
            double2 k01 = *(double2*)&wbest[buf];
            double2 k23 = *(double2*)&wbest[buf + 2];
            double2 k45 = *(double2*)&wbest[buf + 4];
            double2 k67 = *(double2*)&wbest[buf + 6];
            double km = fmax(fmax(fmax(k01.x, k01.y), fmax(k23.x, k23.y)),
                             fmax(fmax(k45.x, k45.y), fmax(k67.x, k67.y)));
            int w = 8191 - (int)(__double_as_longlong(km) & 0x1fff);
            float2 sxy = lds_xy[w];
            sx = sxy.x; sy = sxy.y; sz = lds_z[w];
            if (t == 0) { p2b[3 * i] = sx; p2b[3 * i + 1] = sy; p2b[3 * i + 2] = sz; }
        }
    } else {
        // -------- GEMM: h[r][c] = dot(x[r,:64], W[c,:64]), 128-row tiles, 512 threads --------
        float (*xs)[65] = (float (*)[65])smem;                 // 128x65 f32 = 33280B
        float (*ws)[65] = (float (*)[65])(smem + 33280);       // 128x65 f32 = 33280B
        size_t rowBase = (size_t)(blockIdx.x - B_) * 128;
        for (int idx = t; idx < COUT * CIN; idx += 512) ws[idx >> 6][idx & 63] = W[idx];
        const float* xb = x + rowBase * CIN;
        for (int idx = t; idx < 128 * CIN; idx += 512) xs[idx >> 6][idx & 63] = xb[idx];
        __syncthreads();
        int r0 = (t & 31) * 4, c0 = (t >> 5) * 8;
        float acc[4][8];
#pragma unroll
        for (int i = 0; i < 4; ++i)
#pragma unroll
            for (int j = 0; j < 8; ++j) acc[i][j] = 0.f;
        for (int k = 0; k < CIN; ++k) {
            float xv[4], wvv[8];
#pragma unroll
            for (int i = 0; i < 4; ++i) xv[i] = xs[r0 + i][k];
#pragma unroll
            for (int j = 0; j < 8; ++j) wvv[j] = ws[c0 + j][k];
#pragma unroll
            for (int i = 0; i < 4; ++i)
#pragma unroll
                for (int j = 0; j < 8; ++j) acc[i][j] = fmaf(xv[i], wvv[j], acc[i][j]);
        }
#pragma unroll
        for (int i = 0; i < 4; ++i) {
            size_t o = (rowBase + r0 + i) * COUT + c0;
            *(float4*)&h[o]     = make_float4(acc[i][0], acc[i][1], acc[i][2], acc[i][3]);
            *(float4*)&h[o + 4] = make_float4(acc[i][4], acc[i][5], acc[i][6], acc[i][7]);
        }
    }
}

// ---------------- BN stats (two-stage, deterministic) ----------------
__global__ __launch_bounds__(256) void bn_partial(const float* __restrict__ h, float* __restrict__ psum,
                                                  float* __restrict__ psq) {
    int t = threadIdx.x;
    int c = t & 127, half = t >> 7;
    size_t base = (size_t)blockIdx.x * 256;
    float s = 0.f, q = 0.f;
    for (int it = 0; it < 128; ++it) {
        float v = h[(base + it * 2 + half) * COUT + c];
        s += v; q = fmaf(v, v, q);
    }
    __shared__ float ls[256], lq[256];
    ls[t] = s; lq[t] = q;
    __syncthreads();
    if (t < 128) {
        psum[blockIdx.x * 128 + c] = ls[t] + ls[t + 128];
        psq[blockIdx.x * 128 + c]  = lq[t] + lq[t + 128];
    }
}

__global__ void bn_final(const float* __restrict__ psum, const float* __restrict__ psq,
                         const float* __restrict__ gamma, const float* __restrict__ beta,
                         float* __restrict__ bns) {
    int c = threadIdx.x;  // 128
    float s = 0.f, q = 0.f;
    for (int i = 0; i < 256; ++i) { s += psum[i * 128 + c]; q += psq[i * 128 + c]; }
    float mean = s / 65536.0f;
    float var  = q / 65536.0f - mean * mean;
    float sc = gamma[c] * rsqrtf(var + 1e-5f);
    bns[c] = sc;
    bns[128 + c] = beta[c] - mean * sc;
}

// ---------------- kNN(16) + gather + BN-affine + ReLU + maxpool, one wave per query ----------------
__global__ __launch_bounds__(256) void knn_kernel(const float* __restrict__ p1, const float* __restrict__ p2,
                                                  const float* __restrict__ h, const float* __restrict__ bns,
                                                  float* __restrict__ y) {
    int q = blockIdx.x * 4 + (threadIdx.x >> 6);
    int lane = threadIdx.x & 63;
    int b = q >> 11;             // /M_
    const float* pb = p1 + (size_t)b * N_ * 3;
    const float* pq = p2 + (size_t)q * 3;
    float qx = pq[0], qy = pq[1], qz = pq[2];
    float sqq = __fadd_rn(__fadd_rn(__fmul_rn(qx, qx), __fmul_rn(qy, qy)), __fmul_rn(qz, qz));

    float ld = 1e30f; int li = 0;   // lanes 0..15: distributed sorted top-16
    float tau = 1e30f;

    for (int c0 = 0; c0 < N_; c0 += 64) {
        int cand = c0 + lane;
        float ax = pb[3 * cand], ay = pb[3 * cand + 1], az = pb[3 * cand + 2];
        float s1 = __fadd_rn(__fadd_rn(__fmul_rn(ax, ax), __fmul_rn(ay, ay)), __fmul_rn(az, az));
        float dt = __fadd_rn(__fadd_rn(__fmul_rn(ax, qx), __fmul_rn(ay, qy)), __fmul_rn(az, qz));
        float d  = __fsub_rn(__fadd_rn(sqq, s1), __fmul_rn(2.0f, dt));   // == ref (s2+s1) - 2*dot
        unsigned long long mk = __ballot(d < tau);
        while (mk) {
            int l = __ffsll((unsigned long long)mk) - 1;
            mk &= mk - 1;
            float dd = __shfl(d, l);
            int   ii = c0 + l;
            int pos = __popcll(__ballot(ld <= dd) & 0xFFFFull);  // ties -> after existing (smaller idx kept)
            if (pos < 16) {
                float pd = __shfl_up(ld, 1);
                int   pi = __shfl_up(li, 1);
                if (lane < 16) {
                    if (lane > pos) { ld = pd; li = pi; }
                    if (lane == pos) { ld = dd; li = ii; }
                }
                tau = __shfl(ld, 15);
            }
        }
    }

    // gather 16 neighbor rows, affine+relu+max; each lane owns channels {2*lane, 2*lane+1}
    int c = lane << 1;
    float sc0 = bns[c], sc1 = bns[c + 1];
    float sh0 = bns[128 + c], sh1 = bns[128 + c + 1];
    float a0 = -1e30f, a1 = -1e30f;
#pragma unroll
    for (int t16 = 0; t16 < 16; ++t16) {
        int nb = __shfl(li, t16);
        const float* hp = h + (((size_t)(b * N_ + nb)) << 7) + c;
        float h0 = hp[0], h1 = hp[1];
        a0 = fmaxf(a0, fmaf(h0, sc0, sh0));
        a1 = fmaxf(a1, fmaf(h1, sc1, sh1));
    }
    float2 out = make_float2(fmaxf(a0, 0.f), fmaxf(a1, 0.f));
    *(float2*)&y[((size_t)q << 7) + c] = out;
}

extern "C" void kernel_launch(void* const* d_in, const int* in_sizes, int n_in,
                              void* d_out, int out_size, void* d_ws, size_t ws_size,
                              hipStream_t stream) {
    const float* x     = (const float*)d_in[0];
    const float* p1    = (const float*)d_in[1];
    const float* W     = (const float*)d_in[2];
    const float* gamma = (const float*)d_in[3];
    const float* beta  = (const float*)d_in[4];

    float* y  = (float*)d_out;
    float* p2 = y + (size_t)B_ * M_ * COUT;        // outputs concatenated: y then p2

    float* h    = (float*)d_ws;                    // 65536 x 128 f32 = 32 MB
    float* psum = h + (size_t)B_ * N_ * COUT;
    float* psq  = psum + 256 * 128;
    float* bns  = psq + 256 * 128;

    phase1_kernel<<<B_ + (B_ * N_) / 128, 512, 0, stream>>>(p1, p2, x, W, h);   // FPS ∥ GEMM
    bn_partial<<<256, 256, 0, stream>>>(h, psum, psq);
    bn_final<<<1, 128, 0, stream>>>(psum, psq, gamma, beta, bns);
    knn_kernel<<<(B_ * M_) / 4, 256, 0, stream>>>(p1, p2, h, bns, y);
}

// Round 8
// 2084.362 us; speedup vs baseline: 1.1003x; 1.1003x over previous
//
#include <hip/hip_runtime.h>
#include <cstdint>

#define B_   8
#define N_   8192
#define M_   2048
#define CIN  64
#define COUT 128

typedef unsigned long long u64;

__device__ __forceinline__ float sq3(float dx, float dy, float dz) {
    return __fadd_rn(__fadd_rn(__fmul_rn(dx, dx), __fmul_rn(dy, dy)), __fmul_rn(dz, dz));
}

// One DPP max-reduce step on an f64 key (VALU-only; no LDS pipe).
// CTRL: 0x121=ror1 0x122=ror2 0x124=ror4 0x128=ror8 (within 16-lane row),
//       0x142=row_bcast15, 0x143=row_bcast31. bound_ctrl=false -> invalid lanes keep old.
template<int CTRL>
__device__ __forceinline__ double dppmax(double x) {
    long long b = __double_as_longlong(x);
    int lo = (int)b, hi = (int)(b >> 32);
    int plo = __builtin_amdgcn_update_dpp(lo, lo, CTRL, 0xf, 0xf, false);
    int phi = __builtin_amdgcn_update_dpp(hi, hi, CTRL, 0xf, 0xf, false);
    double p = __longlong_as_double(((long long)(unsigned)phi << 32) | (unsigned)plo);
    return fmax(x, p);
}

// ---------------- phase1: blocks 0..7 = FPS (one/batch), blocks 8..519 = GEMM tiles ----------------
// FPS: 512 thr x 16 pts in registers, point cloud in 96KB static LDS, f64-packed-key argmax
// (key = f64(dist) | (8191-idx) in low mantissa bits -> v_max_f64 == exact (max dist, tie->min idx)).
// Reduce = DPP (ror1,2,4,8 + bcast15,31): lanes 32..63 end with the wave max; lane63 writes LDS.
// p2 store deferred one iteration (rotating writer wave) so the HBM store-ack is off the
// barrier-drain critical path.
__global__ __launch_bounds__(512) void phase1_kernel(const float* __restrict__ p1, float* __restrict__ p2,
                                                     const float* __restrict__ x, const float* __restrict__ W,
                                                     float* __restrict__ h) {
    __shared__ __align__(16) char smem[98432];
    int t = threadIdx.x;

    if (blockIdx.x < B_) {
        // -------- FPS --------
        float2* lds_xy = (float2*)smem;                 // 8192*8B = 64KB
        float*  lds_z  = (float*)(smem + 65536);        // 8192*4B = 32KB
        double* wbest  = (double*)(smem + 98304);       // 2 bufs x 8 waves

        int b = blockIdx.x;
        const float* pb = p1 + (size_t)b * N_ * 3;
        float* p2b = p2 + (size_t)b * M_ * 3;
        int lane = t & 63, wave = t >> 6;

        for (int i = t; i < N_; i += 512) {
            lds_xy[i] = make_float2(pb[3 * i], pb[3 * i + 1]);
            lds_z[i]  = pb[3 * i + 2];
        }
        __syncthreads();

        // resident points + dists in registers (idx = t + j*512): 16x4 = 64 VGPRs
        float px[16], py[16], pz[16], dist[16];
#pragma unroll
        for (int j = 0; j < 16; ++j) {
            int idx = t + j * 512;
            float2 xy = lds_xy[idx];
            px[j] = xy.x; py[j] = xy.y; pz[j] = lds_z[idx];
            dist[j] = 1e10f;
        }

        float2 s0 = lds_xy[0];
        float sx = s0.x, sy = s0.y, sz = lds_z[0];   // selection 0 (stored deferred at i=1)

        for (int i = 1; i < M_; ++i) {
            // deferred store of selection i-1 by rotating wave -> store-ack hides under this iter
            if (t == ((i & 7) << 6)) {
                p2b[3 * (i - 1)] = sx; p2b[3 * (i - 1) + 1] = sy; p2b[3 * (i - 1) + 2] = sz;
            }
            float bestv = -1.0f; int besti = 0;
#pragma unroll
            for (int j = 0; j < 16; ++j) {
                float d = sq3(__fsub_rn(px[j], sx), __fsub_rn(py[j], sy), __fsub_rn(pz[j], sz));
                float nd = fminf(dist[j], d);
                dist[j] = nd;
                if (nd > bestv) { bestv = nd; besti = t + j * 512; }  // strict >: first occurrence
            }
            // f64 key: exact value ordering, tie -> min index
            double key = __longlong_as_double(__double_as_longlong((double)bestv) | (u64)(8191 - besti));
            key = dppmax<0x121>(key);   // ror:1
            key = dppmax<0x122>(key);   // ror:2
            key = dppmax<0x124>(key);   // ror:4
            key = dppmax<0x128>(key);   // ror:8  -> every lane has its row16 max
            key = dppmax<0x142>(key);   // bcast15: rows 1,3 absorb rows 0,2
            key = dppmax<0x143>(key);   // bcast31: lanes 32..63 have wave max
            int buf = (i & 1) << 3;                      // double-buffer -> 1 barrier/iter
            if (lane == 63) wbest[buf + wave] = key;
            __syncthreads();
            double2 k01 = *(double2*)&wbest[buf];
            double2 k23 = *(double2*)&wbest[buf + 2];
            double2 k45 = *(double2*)&wbest[buf + 4];
            double2 k67 = *(double2*)&wbest[buf + 6];
            double km = fmax(fmax(fmax(k01.x, k01.y), fmax(k23.x, k23.y)),
                             fmax(fmax(k45.x, k45.y), fmax(k67.x, k67.y)));
            int w = 8191 - (int)(__double_as_longlong(km) & 0x1fff);
            float2 sxy = lds_xy[w];
            sx = sxy.x; sy = sxy.y; sz = lds_z[w];
        }
        if (t == 0) {   // final selection M-1
            p2b[3 * (M_ - 1)] = sx; p2b[3 * (M_ - 1) + 1] = sy; p2b[3 * (M_ - 1) + 2] = sz;
        }
    } else {
        // -------- GEMM: h[r][c] = dot(x[r,:64], W[c,:64]), 128-row tiles, 512 threads --------
        float (*xs)[65] = (float (*)[65])smem;                 // 128x65 f32 = 33280B
        float (*ws)[65] = (float (*)[65])(smem + 33280);       // 128x65 f32 = 33280B
        size_t rowBase = (size_t)(blockIdx.x - B_) * 128;
        for (int idx = t; idx < COUT * CIN; idx += 512) ws[idx >> 6][idx & 63] = W[idx];
        const float* xb = x + rowBase * CIN;
        for (int idx = t; idx < 128 * CIN; idx += 512) xs[idx >> 6][idx & 63] = xb[idx];
        __syncthreads();
        int r0 = (t & 31) * 4, c0 = (t >> 5) * 8;
        float acc[4][8];
#pragma unroll
        for (int i = 0; i < 4; ++i)
#pragma unroll
            for (int j = 0; j < 8; ++j) acc[i][j] = 0.f;
        for (int k = 0; k < CIN; ++k) {
            float xv[4], wvv[8];
#pragma unroll
            for (int i = 0; i < 4; ++i) xv[i] = xs[r0 + i][k];
#pragma unroll
            for (int j = 0; j < 8; ++j) wvv[j] = ws[c0 + j][k];
#pragma unroll
            for (int i = 0; i < 4; ++i)
#pragma unroll
                for (int j = 0; j < 8; ++j) acc[i][j] = fmaf(xv[i], wvv[j], acc[i][j]);
        }
#pragma unroll
        for (int i = 0; i < 4; ++i) {
            size_t o = (rowBase + r0 + i) * COUT + c0;
            *(float4*)&h[o]     = make_float4(acc[i][0], acc[i][1], acc[i][2], acc[i][3]);
            *(float4*)&h[o + 4] = make_float4(acc[i][4], acc[i][5], acc[i][6], acc[i][7]);
        }
    }
}

// ---------------- BN stats (two-stage, deterministic) ----------------
__global__ __launch_bounds__(256) void bn_partial(const float* __restrict__ h, float* __restrict__ psum,
                                                  float* __restrict__ psq) {
    int t = threadIdx.x;
    int c = t & 127, half = t >> 7;
    size_t base = (size_t)blockIdx.x * 256;
    float s = 0.f, q = 0.f;
    for (int it = 0; it < 128; ++it) {
        float v = h[(base + it * 2 + half) * COUT + c];
        s += v; q = fmaf(v, v, q);
    }
    __shared__ float ls[256], lq[256];
    ls[t] = s; lq[t] = q;
    __syncthreads();
    if (t < 128) {
        psum[blockIdx.x * 128 + c] = ls[t] + ls[t + 128];
        psq[blockIdx.x * 128 + c]  = lq[t] + lq[t + 128];
    }
}

__global__ void bn_final(const float* __restrict__ psum, const float* __restrict__ psq,
                         const float* __restrict__ gamma, const float* __restrict__ beta,
                         float* __restrict__ bns) {
    int c = threadIdx.x;  // 128
    float s = 0.f, q = 0.f;
    for (int i = 0; i < 256; ++i) { s += psum[i * 128 + c]; q += psq[i * 128 + c]; }
    float mean = s / 65536.0f;
    float var  = q / 65536.0f - mean * mean;
    float sc = gamma[c] * rsqrtf(var + 1e-5f);
    bns[c] = sc;
    bns[128 + c] = beta[c] - mean * sc;
}

// ---------------- kNN(16) + gather + BN-affine + ReLU + maxpool, one wave per query ----------------
__global__ __launch_bounds__(256) void knn_kernel(const float* __restrict__ p1, const float* __restrict__ p2,
                                                  const float* __restrict__ h, const float* __restrict__ bns,
                                                  float* __restrict__ y) {
    int q = blockIdx.x * 4 + (threadIdx.x >> 6);
    int lane = threadIdx.x & 63;
    int b = q >> 11;             // /M_
    const float* pb = p1 + (size_t)b * N_ * 3;
    const float* pq = p2 + (size_t)q * 3;
    float qx = pq[0], qy = pq[1], qz = pq[2];
    float sqq = __fadd_rn(__fadd_rn(__fmul_rn(qx, qx), __fmul_rn(qy, qy)), __fmul_rn(qz, qz));

    float ld = 1e30f; int li = 0;   // lanes 0..15: distributed sorted top-16
    float tau = 1e30f;

    for (int c0 = 0; c0 < N_; c0 += 64) {
        int cand = c0 + lane;
        float ax = pb[3 * cand], ay = pb[3 * cand + 1], az = pb[3 * cand + 2];
        float s1 = __fadd_rn(__fadd_rn(__fmul_rn(ax, ax), __fmul_rn(ay, ay)), __fmul_rn(az, az));
        float dt = __fadd_rn(__fadd_rn(__fmul_rn(ax, qx), __fmul_rn(ay, qy)), __fmul_rn(az, qz));
        float d  = __fsub_rn(__fadd_rn(sqq, s1), __fmul_rn(2.0f, dt));   // == ref (s2+s1) - 2*dot
        unsigned long long mk = __ballot(d < tau);
        while (mk) {
            int l = __ffsll((unsigned long long)mk) - 1;
            mk &= mk - 1;
            float dd = __shfl(d, l);
            int   ii = c0 + l;
            int pos = __popcll(__ballot(ld <= dd) & 0xFFFFull);  // ties -> after existing (smaller idx kept)
            if (pos < 16) {
                float pd = __shfl_up(ld, 1);
                int   pi = __shfl_up(li, 1);
                if (lane < 16) {
                    if (lane > pos) { ld = pd; li = pi; }
                    if (lane == pos) { ld = dd; li = ii; }
                }
                tau = __shfl(ld, 15);
            }
        }
    }

    // gather 16 neighbor rows, affine+relu+max; each lane owns channels {2*lane, 2*lane+1}
    int c = lane << 1;
    float sc0 = bns[c], sc1 = bns[c + 1];
    float sh0 = bns[128 + c], sh1 = bns[128 + c + 1];
    float a0 = -1e30f, a1 = -1e30f;
#pragma unroll
    for (int t16 = 0; t16 < 16; ++t16) {
        int nb = __shfl(li, t16);
        const float* hp = h + (((size_t)(b * N_ + nb)) << 7) + c;
        float h0 = hp[0], h1 = hp[1];
        a0 = fmaxf(a0, fmaf(h0, sc0, sh0));
        a1 = fmaxf(a1, fmaf(h1, sc1, sh1));
    }
    float2 out = make_float2(fmaxf(a0, 0.f), fmaxf(a1, 0.f));
    *(float2*)&y[((size_t)q << 7) + c] = out;
}

extern "C" void kernel_launch(void* const* d_in, const int* in_sizes, int n_in,
                              void* d_out, int out_size, void* d_ws, size_t ws_size,
                              hipStream_t stream) {
    const float* x     = (const float*)d_in[0];
    const float* p1    = (const float*)d_in[1];
    const float* W     = (const float*)d_in[2];
    const float* gamma = (const float*)d_in[3];
    const float* beta  = (const float*)d_in[4];

    float* y  = (float*)d_out;
    float* p2 = y + (size_t)B_ * M_ * COUT;        // outputs concatenated: y then p2

    float* h    = (float*)d_ws;                    // 65536 x 128 f32 = 32 MB
    float* psum = h + (size_t)B_ * N_ * COUT;
    float* psq  = psum + 256 * 128;
    float* bns  = psq + 256 * 128;

    phase1_kernel<<<B_ + (B_ * N_) / 128, 512, 0, stream>>>(p1, p2, x, W, h);   // FPS ∥ GEMM
    bn_partial<<<256, 256, 0, stream>>>(h, psum, psq);
    bn_final<<<1, 128, 0, stream>>>(psum, psq, gamma, beta, bns);
    knn_kernel<<<(B_ * M_) / 4, 256, 0, stream>>>(p1, p2, h, bns, y);
}